// Round 8
// baseline (555.305 us; speedup 1.0000x reference)
//
#include <hip/hip_runtime.h>

#define NB 8
#define NS 1024
#define NH 32
#define NKV 8
#define ND 128
#define QT 128     // per block: 4 waves x 32 q-rows
#define KT 64

typedef _Float16 f16x8 __attribute__((ext_vector_type(8)));
typedef _Float16 f16x4 __attribute__((ext_vector_type(4)));
typedef _Float16 f16x2 __attribute__((ext_vector_type(2)));
typedef __fp16 fp16x2 __attribute__((ext_vector_type(2)));
typedef float f32x16 __attribute__((ext_vector_type(16)));
typedef unsigned int u32x2 __attribute__((ext_vector_type(2)));

__device__ __forceinline__ float exp2fast(float x) { return __builtin_amdgcn_exp2f(x); }

__device__ __forceinline__ unsigned pkrtz_u(float a, float b) {
  union { fp16x2 h; unsigned u; } c;
  c.h = __builtin_amdgcn_cvt_pkrtz(a, b);
  return c.u;
}
__device__ __forceinline__ u32x2 swap32(float x) {
  union { float f; unsigned u; } c; c.f = x;
  return __builtin_amdgcn_permlane32_swap(c.u, c.u, false, false);
}
__device__ __forceinline__ float asf(unsigned u) { union { unsigned u; float f; } c; c.u = u; return c.f; }
// 3-bit chunk swizzle for 128B V^T rows
__device__ __forceinline__ int gsw3(int d) { return ((d ^ (d >> 3)) & 7) << 4; }

__global__ __launch_bounds__(256, 3)   // cap total regs at 170 (3 waves/EU); (·,4) would force 128 and spill (R6)
void attn_fwd(const float* __restrict__ qg, const float* __restrict__ kg,
              const float* __restrict__ vg, float* __restrict__ og)
{
  // single-buffered: K 16KB (64 rows x 256B, byte ^= (kv&15)<<4),
  //                  V^T 16KB (128 d-rows x 128B, chunk ^= gsw3(d))   -> 32KB total
  __shared__ __align__(16) _Float16 Klds[KT * 128];
  __shared__ __align__(16) _Float16 VTlds[128 * 64];

  const int tid  = threadIdx.x;
  const int lane = tid & 63;
  const int w    = tid >> 6;
  const int lq   = lane & 31;
  const int hi   = lane >> 5;

  const int qtile = blockIdx.x;   // 0..7
  const int b     = blockIdx.y;
  const int h     = blockIdx.z;
  const int hkv   = h >> 2;

  const int qr0w = qtile * QT + w * 32;
  const int qrow = qr0w + lq;

  const float QS = 0.08838834764831845f * 1.4426950408889634f;  // scale * log2(e)

  // ---- Q fragments (B-frag: col=q=lane&31, k = 8*hi + i per 16-d block) ----
  f16x8 qf[8];
  {
    const float* qp = qg + (size_t)(b * NS + qrow) * (NH * ND) + h * ND + hi * 8;
#pragma unroll
    for (int dblk = 0; dblk < 8; ++dblk) {
      float4 f0 = *(const float4*)(qp + dblk * 16);
      float4 f1 = *(const float4*)(qp + dblk * 16 + 4);
      f16x8 a;
      a[0] = (_Float16)(f0.x * QS); a[1] = (_Float16)(f0.y * QS);
      a[2] = (_Float16)(f0.z * QS); a[3] = (_Float16)(f0.w * QS);
      a[4] = (_Float16)(f1.x * QS); a[5] = (_Float16)(f1.y * QS);
      a[6] = (_Float16)(f1.z * QS); a[7] = (_Float16)(f1.w * QS);
      qf[dblk] = a;
    }
  }

  f32x16 acc[4];
#pragma unroll
  for (int nb = 0; nb < 4; ++nb)
#pragma unroll
    for (int r = 0; r < 16; ++r) acc[nb][r] = 0.f;
  float m_run = -1e30f, l_run = 0.f;

  const float* kbase0 = kg + (size_t)(b * NS) * (NKV * ND) + hkv * ND;
  const float* vbase0 = vg + (size_t)(b * NS) * (NKV * ND) + hkv * ND;

  const int d4_s = (tid & 31) * 4;

  const int nt = 2 * (qtile + 1);
  for (int ti = 0; ti < nt; ++ti) {
    const int kv0 = ti * KT;

    // ---- stage K tile (64x128 f32 -> f16, swizzled): 8 rows per pass ----
    {
      const float* kb_ = kbase0 + (size_t)kv0 * (NKV * ND);
#pragma unroll
      for (int it = 0; it < 8; ++it) {
        int f   = tid + it * 256;
        int kvr = f >> 5;
        float4 kk = *(const float4*)(kb_ + (size_t)kvr * (NKV * ND) + d4_s);
        union { f16x4 h; unsigned long long u; } pk;
        pk.h[0] = (_Float16)kk.x; pk.h[1] = (_Float16)kk.y;
        pk.h[2] = (_Float16)kk.z; pk.h[3] = (_Float16)kk.w;
        *(unsigned long long*)((char*)Klds + kvr * 256 + ((d4_s * 2) ^ ((kvr & 15) << 4))) = pk.u;
      }
    }
    // ---- stage V^T (kv-quad transpose -> b64 writes, swizzled): 32 rows per pass ----
    {
      const float* vb_ = vbase0 + (size_t)kv0 * (NKV * ND);
#pragma unroll
      for (int it = 0; it < 2; ++it) {
        int kvq = (tid >> 5) + it * 8;       // kv quad 0..15
        float4 v0 = *(const float4*)(vb_ + (size_t)(4 * kvq + 0) * (NKV * ND) + d4_s);
        float4 v1 = *(const float4*)(vb_ + (size_t)(4 * kvq + 1) * (NKV * ND) + d4_s);
        float4 v2 = *(const float4*)(vb_ + (size_t)(4 * kvq + 2) * (NKV * ND) + d4_s);
        float4 v3 = *(const float4*)(vb_ + (size_t)(4 * kvq + 3) * (NKV * ND) + d4_s);
        float e0[4] = {v0.x, v0.y, v0.z, v0.w};
        float e1[4] = {v1.x, v1.y, v1.z, v1.w};
        float e2[4] = {v2.x, v2.y, v2.z, v2.w};
        float e3[4] = {v3.x, v3.y, v3.z, v3.w};
#pragma unroll
        for (int i = 0; i < 4; ++i) {
          int d = d4_s + i;
          union { f16x4 h; unsigned long long u; } pv;
          pv.h[0] = (_Float16)e0[i]; pv.h[1] = (_Float16)e1[i];
          pv.h[2] = (_Float16)e2[i]; pv.h[3] = (_Float16)e3[i];
          *(unsigned long long*)((char*)VTlds + d * 128 + ((kvq * 8) ^ gsw3(d))) = pv.u;
        }
      }
    }
    __syncthreads();

    if (kv0 <= qr0w + 31) {          // wave-uniform causal tile skip
      // ---- swapped QK^T: P^T[kv][q] ----
      f32x16 s[2];
#pragma unroll
      for (int r = 0; r < 16; ++r) { s[0][r] = 0.f; s[1][r] = 0.f; }
      __builtin_amdgcn_s_setprio(1);
#pragma unroll
      for (int dblk = 0; dblk < 8; ++dblk) {
        int soff = (dblk * 32 + 16 * hi) ^ ((lq & 15) << 4);
        f16x8 k0 = *(const f16x8*)((const char*)Klds + lq * 256 + soff);
        f16x8 k1 = *(const f16x8*)((const char*)Klds + (lq + 32) * 256 + soff);
        s[0] = __builtin_amdgcn_mfma_f32_32x32x16_f16(k0, qf[dblk], s[0], 0, 0, 0);
        s[1] = __builtin_amdgcn_mfma_f32_32x32x16_f16(k1, qf[dblk], s[1], 0, 0, 0);
      }
      __builtin_amdgcn_s_setprio(0);

      // ---- causal mask (diagonal tiles only) ----
      if (kv0 + KT - 1 > qr0w) {
        const int thr = qrow - kv0;
#pragma unroll
        for (int kb = 0; kb < 2; ++kb)
#pragma unroll
          for (int r = 0; r < 16; ++r) {
            int kvl = kb * 32 + (r & 3) + 8 * (r >> 2) + 4 * hi;
            if (kvl > thr) s[kb][r] = -1e30f;
          }
      }

      // ---- online softmax with defer-max (T13, THR=8 in log2 units) ----
      float pmax = s[0][0];
#pragma unroll
      for (int r = 1; r < 16; ++r) pmax = fmaxf(pmax, s[0][r]);
#pragma unroll
      for (int r = 0; r < 16; ++r) pmax = fmaxf(pmax, s[1][r]);
      {
        u32x2 pr = swap32(pmax);
        pmax = fmaxf(asf(pr[0]), asf(pr[1]));
      }
      const int need = !__all(pmax <= m_run + 8.0f);
      if (need) {
        const float mn = fmaxf(m_run, pmax);
        const float al = exp2fast(m_run - mn);
        m_run = mn;
#pragma unroll
        for (int r = 0; r < 16; ++r) {
          int row = (r & 3) + 8 * (r >> 2) + 4 * hi;
          float a = __shfl(al, row, 64);
#pragma unroll
          for (int nb = 0; nb < 4; ++nb) acc[nb][r] *= a;
        }
        l_run *= al;
      }
      float rs = 0.f;
#pragma unroll
      for (int kb = 0; kb < 2; ++kb)
#pragma unroll
        for (int r = 0; r < 16; ++r) {
          float p = exp2fast(s[kb][r] - m_run);
          s[kb][r] = p;
          rs += p;
        }
      {
        u32x2 sr = swap32(rs);
        rs = asf(sr[0]) + asf(sr[1]);
      }
      l_run += rs;

      // ---- P -> A-fragments in-register (cvt_pk + permlane32_swap) ----
      f16x8 pa[4];
#pragma unroll
      for (int t = 0; t < 4; ++t) {
        const int kb = t >> 1, rb = (t & 1) * 8;
        unsigned w0 = pkrtz_u(s[kb][rb + 0], s[kb][rb + 1]);
        unsigned w1 = pkrtz_u(s[kb][rb + 2], s[kb][rb + 3]);
        unsigned w2 = pkrtz_u(s[kb][rb + 4], s[kb][rb + 5]);
        unsigned w3 = pkrtz_u(s[kb][rb + 6], s[kb][rb + 7]);
        u32x2 p02 = __builtin_amdgcn_permlane32_swap(w0, w2, false, false);
        u32x2 p13 = __builtin_amdgcn_permlane32_swap(w1, w3, false, false);
        union { unsigned u[4]; f16x8 v; } pw;
        pw.u[0] = p02[0]; pw.u[1] = p13[0]; pw.u[2] = p02[1]; pw.u[3] = p13[1];
        pa[t] = pw.v;
      }

      // ---- O += P V ----
      __builtin_amdgcn_s_setprio(1);
#pragma unroll
      for (int t = 0; t < 4; ++t) {
        int koff = t * 32 + 16 * hi;
#pragma unroll
        for (int nb = 0; nb < 4; ++nb) {
          int d = nb * 32 + lq;
          f16x8 vb = *(const f16x8*)((const char*)VTlds + d * 128 + (koff ^ gsw3(d)));
          acc[nb] = __builtin_amdgcn_mfma_f32_32x32x16_f16(pa[t], vb, acc[nb], 0, 0, 0);
        }
      }
      __builtin_amdgcn_s_setprio(0);
    }
    __syncthreads();                  // protect buffer before next stage
  }

  // ---- epilogue: divide by l, coalesced f32 stores ----
  const float linv = 1.0f / l_run;
#pragma unroll
  for (int r = 0; r < 16; ++r) {
    int row = (r & 3) + 8 * (r >> 2) + 4 * hi;
    float li = __shfl(linv, row, 64);
    float* op = og + (size_t)(b * NS + qr0w + row) * (NH * ND) + h * ND + lq;
#pragma unroll
    for (int nb = 0; nb < 4; ++nb)
      op[nb * 32] = acc[nb][r] * li;
  }
}

extern "C" void kernel_launch(void* const* d_in, const int* in_sizes, int n_in,
                              void* d_out, int out_size, void* d_ws, size_t ws_size,
                              hipStream_t stream) {
  const float* q = (const float*)d_in[0];
  const float* k = (const float*)d_in[1];
  const float* v = (const float*)d_in[2];
  float* o = (float*)d_out;
  dim3 grid(NS / QT, NB, NH);
  attn_fwd<<<grid, 256, 0, stream>>>(q, k, v, o);
}